// Round 1
// 287.963 us; speedup vs baseline: 1.0228x; 1.0228x over previous
//
#include <hip/hip_runtime.h>
#include <stdint.h>

// SelfAttentionLayer: x [32,32,32,512] fp32 -> out fp32 same shape
#define B_ 32
#define N_ 1024   // tokens per batch (H*W)
#define C_ 512
#define D_ 64     // DQK

typedef __attribute__((ext_vector_type(8))) __bf16 bf8;   // MFMA A/B frag (4 VGPRs)
typedef __attribute__((ext_vector_type(4))) float f32x4;  // MFMA C/D frag

typedef const __attribute__((address_space(1))) void* gp_t;
typedef __attribute__((address_space(3))) void* lp_t;

__device__ inline void g2l16(const void* g, void* l) {
    // async global->LDS, 16B/lane; LDS dest = uniform base + lane*16
    __builtin_amdgcn_global_load_lds((gp_t)g, (lp_t)l, 16, 0, 0);
}

__device__ inline float b2f(unsigned short u) {
    return __uint_as_float(((unsigned)u) << 16);
}
__device__ inline unsigned short f2b(float f) {   // f32 -> bf16 bits, RNE
    unsigned u = __float_as_uint(f);
    u += 0x7FFF + ((u >> 16) & 1);
    return (unsigned short)(u >> 16);
}

#define MFMA16(a, b, c) __builtin_amdgcn_mfma_f32_16x16x32_bf16((a), (b), (c), 0, 0, 0)

// ---------------------------------------------------------------------------
// Kernel 0: x fp32 -> bf16 (so qkv can stage via global_load_lds)
// ---------------------------------------------------------------------------
__global__ __launch_bounds__(256) void xcvt(const float* __restrict__ x,
                                            unsigned short* __restrict__ xb) {
    int i = blockIdx.x * 256 + threadIdx.x;      // quad index, exact grid
    float4 f = ((const float4*)x)[i];
    ushort4 o;
    o.x = f2b(f.x); o.y = f2b(f.y); o.z = f2b(f.z); o.w = f2b(f.w);
    ((ushort4*)xb)[i] = o;
}

// ---------------------------------------------------------------------------
// Kernel 0b: weight transpose + cvt into concatenated WT[640][512] bf16.
// One launch for all three weight matrices (wq rows 0..63, wk 64..127,
// wv 128..639).  w[cin=512][cout] f32 -> WT[co][512].
// ---------------------------------------------------------------------------
__global__ __launch_bounds__(256) void wtrans_all(
    const float* __restrict__ wq, const float* __restrict__ wk,
    const float* __restrict__ wv, unsigned short* __restrict__ wt)
{
    int t = blockIdx.x * 256 + threadIdx.x;      // output-linear, exact grid (640*512)
    int co = t >> 9;          // /512
    int ci = t & 511;
    const float* src;
    int col, cout;
    if (co < 64)       { src = wq; col = co;       cout = 64;  }
    else if (co < 128) { src = wk; col = co - 64;  cout = 64;  }
    else               { src = wv; col = co - 128; cout = 512; }
    wt[t] = f2b(src[(size_t)ci * cout + col]);
}

// ---------------------------------------------------------------------------
// Kernel 1: QKV projection GEMM. [32768,512]bf16 @ WT[640,512]^T.
// Block tile 128x128, waves 2x2 (64x64 each), BK=64, both operands staged
// fragment-order via global_load_lds.  2-phase double-buffered prefetch:
// per K-step {ds_read frags(t) | sched_barrier | stage(t+1) | MFMA | barrier}.
// grid = (256 rowblocks, 5 colblocks): cb 0 -> q|k cols, cb 1..4 -> v cols.
// v written transposed vT[b][c][n] via LDS transpose buffer (aliased).
// ---------------------------------------------------------------------------
__global__ __launch_bounds__(256) void qkv(
    const unsigned short* __restrict__ xb,
    const unsigned short* __restrict__ WT,
    const float* __restrict__ bq, const float* __restrict__ bk,
    const float* __restrict__ bv,
    unsigned short* __restrict__ q, unsigned short* __restrict__ k,
    unsigned short* __restrict__ vT)
{
    const int rb = blockIdx.x;
    const int cb = blockIdx.y;
    const int tid = threadIdx.x;
    const int lane = tid & 63;
    const int wave = tid >> 6;
    const int wm = wave >> 1, wn = wave & 1;
    const int lr = lane & 15;     // frag row/col within 16
    const int lk = lane >> 4;     // k-octet 0..3

    __shared__ unsigned short SM[32768];      // 64 KB: As[2][8192] | Bs[2][8192]
    unsigned short* TB = SM;                  // aliased transpose buf 128x132 (16896)

    const int row0 = rb * 128;
    const int col0 = cb * 128;                // within [640]

    f32x4 zero4 = {0.f, 0.f, 0.f, 0.f};
    f32x4 acc[4][4];
    #pragma unroll
    for (int i = 0; i < 4; ++i)
        #pragma unroll
        for (int j = 0; j < 4; ++j) acc[i][j] = zero4;

    auto stage = [&](int buf, int kk) {
        unsigned short* As = SM + buf * 8192;
        unsigned short* Bs = SM + 16384 + buf * 8192;
        #pragma unroll
        for (int i = 0; i < 4; ++i) {          // 16 frags each for A and B
            int f = wave * 4 + i;
            int t = f >> 1, kq = f & 1;
            g2l16(xb + (size_t)(row0 + t * 16 + lr) * C_ + kk + kq * 32 + lk * 8,
                  &As[f * 512]);
            g2l16(WT + (size_t)(col0 + t * 16 + lr) * C_ + kk + kq * 32 + lk * 8,
                  &Bs[f * 512]);
        }
    };

    stage(0, 0);
    __syncthreads();                           // vmcnt(0) drain at barrier
    int cur = 0;
    for (int kk = 64; kk < C_; kk += 64) {
        const unsigned short* As = SM + cur * 8192;
        const unsigned short* Bs = SM + 16384 + cur * 8192;
        bf8 a[2][4], bb[2][4];
        #pragma unroll
        for (int kq = 0; kq < 2; ++kq) {
            #pragma unroll
            for (int ti = 0; ti < 4; ++ti)
                a[kq][ti] = *(const bf8*)&As[((wm * 4 + ti) * 2 + kq) * 512 + lane * 8];
            #pragma unroll
            for (int tj = 0; tj < 4; ++tj)
                bb[kq][tj] = *(const bf8*)&Bs[((wn * 4 + tj) * 2 + kq) * 512 + lane * 8];
        }
        // pin: ds_reads stay above the LDS-writing prefetch (no vmcnt before them)
        __builtin_amdgcn_sched_barrier(0);
        stage(cur ^ 1, kk);                    // prefetch next tile; drains at barrier
        #pragma unroll
        for (int kq = 0; kq < 2; ++kq)
            #pragma unroll
            for (int ti = 0; ti < 4; ++ti)
                #pragma unroll
                for (int tj = 0; tj < 4; ++tj)
                    acc[ti][tj] = MFMA16(a[kq][ti], bb[kq][tj], acc[ti][tj]);
        __syncthreads();
        cur ^= 1;
    }
    {   // tail: compute last staged tile (no prefetch)
        const unsigned short* As = SM + cur * 8192;
        const unsigned short* Bs = SM + 16384 + cur * 8192;
        #pragma unroll
        for (int kq = 0; kq < 2; ++kq) {
            bf8 a[4], bb[4];
            #pragma unroll
            for (int ti = 0; ti < 4; ++ti)
                a[ti] = *(const bf8*)&As[((wm * 4 + ti) * 2 + kq) * 512 + lane * 8];
            #pragma unroll
            for (int tj = 0; tj < 4; ++tj)
                bb[tj] = *(const bf8*)&Bs[((wn * 4 + tj) * 2 + kq) * 512 + lane * 8];
            #pragma unroll
            for (int ti = 0; ti < 4; ++ti)
                #pragma unroll
                for (int tj = 0; tj < 4; ++tj)
                    acc[ti][tj] = MFMA16(a[ti], bb[tj], acc[ti][tj]);
        }
    }

    if (cb == 0) {
        // wn==0 waves own cols 0..63 (-> q), wn==1 own cols 64..127 (-> k)
        unsigned short* outp = (wn == 0) ? q : k;
        const float* bias = (wn == 0) ? bq : bk;
        #pragma unroll
        for (int ti = 0; ti < 4; ++ti)
            #pragma unroll
            for (int tj = 0; tj < 4; ++tj) {
                int col = tj * 16 + lr;           // 0..63 within q or k
                float bi = bias[col];
                #pragma unroll
                for (int r = 0; r < 4; ++r) {
                    int row = row0 + wm * 64 + ti * 16 + lk * 4 + r;
                    outp[(size_t)row * D_ + col] = f2b(acc[ti][tj][r] + bi);
                }
            }
    } else {
        const int colv = (cb - 1) * 128;          // v col base (0..511)
        __syncthreads();                          // As/Bs reads done; TB aliases
        #pragma unroll
        for (int ti = 0; ti < 4; ++ti)
            #pragma unroll
            for (int tj = 0; tj < 4; ++tj) {
                int c = wn * 64 + tj * 16 + lr;   // 0..127 within block
                float bi = bv[colv + c];
                int tok = wm * 64 + ti * 16 + lk * 4;
                ushort4 o;
                o.x = f2b(acc[ti][tj][0] + bi);
                o.y = f2b(acc[ti][tj][1] + bi);
                o.z = f2b(acc[ti][tj][2] + bi);
                o.w = f2b(acc[ti][tj][3] + bi);
                *(ushort4*)&TB[c * 132 + tok] = o;
            }
        __syncthreads();
        const int b  = row0 >> 10;
        const int n0 = row0 & 1023;
        #pragma unroll
        for (int i = 0; i < 16; ++i) {
            int idx = tid + 256 * i;              // 0..4095
            int c = idx >> 5, ch = idx & 31;
            ushort4 t4 = *(const ushort4*)&TB[c * 132 + ch * 4];
            *(ushort4*)&vT[((size_t)(b * C_ + colv + c)) * N_ + n0 + ch * 4] = t4;
        }
    }
}

// ---------------------------------------------------------------------------
// Kernel 2: scores + softmax -> P bf16 [b][n][m].
// Block: one batch, 16 query rows. Waves split m (256 each). S strip in LDS
// as bf16 (33 KB incl pad -> 4 blocks/CU).  grid = (64 qtiles, 32 batches)
// ---------------------------------------------------------------------------
#define SLD 1032   // S leading dim (shorts), pad 8 to break 2048B bank period
__global__ __launch_bounds__(256) void scores(
    const unsigned short* __restrict__ q,
    const unsigned short* __restrict__ k,
    unsigned short* __restrict__ P)
{
    const int qt = blockIdx.x, b = blockIdx.y;
    const int tid = threadIdx.x, lane = tid & 63, wave = tid >> 6;
    const int lr = lane & 15, lk = lane >> 4;
    __shared__ unsigned short S[16 * SLD];      // bf16 scores, 33 KB

    const int n0 = qt * 16;
    const unsigned short* qrow = q + (size_t)(b * N_ + n0 + lr) * D_ + lk * 8;
    bf8 qa0 = *(const bf8*)(qrow);
    bf8 qa1 = *(const bf8*)(qrow + 32);

    const int m0w = wave * 256;
    #pragma unroll 4
    for (int mt = 0; mt < 16; ++mt) {
        int m = m0w + mt * 16;
        const unsigned short* krow = k + (size_t)(b * N_ + m + lr) * D_ + lk * 8;
        bf8 kb0 = *(const bf8*)(krow);
        bf8 kb1 = *(const bf8*)(krow + 32);
        f32x4 s = {0.f, 0.f, 0.f, 0.f};
        s = MFMA16(qa0, kb0, s);
        s = MFMA16(qa1, kb1, s);
        #pragma unroll
        for (int r = 0; r < 4; ++r)
            S[(lk * 4 + r) * SLD + m + lr] = f2b(s[r] * 0.125f);  // 1/sqrt(64)
    }
    __syncthreads();

    #pragma unroll
    for (int rr4 = 0; rr4 < 4; ++rr4) {
        int rr = wave * 4 + rr4;
        float vals[16];
        float mx = -1e30f;
        #pragma unroll
        for (int j = 0; j < 16; ++j) {
            vals[j] = b2f(S[rr * SLD + j * 64 + lane]);
            mx = fmaxf(mx, vals[j]);
        }
        #pragma unroll
        for (int off = 32; off; off >>= 1) mx = fmaxf(mx, __shfl_xor(mx, off));
        float sum = 0.f;
        #pragma unroll
        for (int j = 0; j < 16; ++j) { vals[j] = __expf(vals[j] - mx); sum += vals[j]; }
        #pragma unroll
        for (int off = 32; off; off >>= 1) sum += __shfl_xor(sum, off);
        float inv = 1.f / sum;
        unsigned short* pp = P + (size_t)(b * N_ + n0 + rr) * N_;
        #pragma unroll
        for (int j = 0; j < 16; ++j) pp[j * 64 + lane] = f2b(vals[j] * inv);
    }
}

// ---------------------------------------------------------------------------
// Kernel 3: O = P @ V + x (residual), fp32 out. Per-batch GEMM M=1024 N=512
// K=1024. Block tile 128x128, waves 2x2, BK=64, both operands staged
// fragment-order via global_load_lds.  2-phase double-buffered prefetch
// (same schedule as qkv).  grid = (8, 4, 32)
// ---------------------------------------------------------------------------
__global__ __launch_bounds__(256) void pv(
    const unsigned short* __restrict__ P,
    const unsigned short* __restrict__ vT,
    const float* __restrict__ x,
    float* __restrict__ out)
{
    const int m0 = blockIdx.x * 128, c0 = blockIdx.y * 128, b = blockIdx.z;
    const int tid = threadIdx.x, lane = tid & 63, wave = tid >> 6;
    const int wm = wave >> 1, wn = wave & 1;
    const int lr = lane & 15, lk = lane >> 4;

    __shared__ unsigned short As[2][8192];   // P frags, double-buffered
    __shared__ unsigned short Bs[2][8192];   // V frags, double-buffered

    f32x4 zero4 = {0.f, 0.f, 0.f, 0.f};
    f32x4 acc[4][4];
    #pragma unroll
    for (int i = 0; i < 4; ++i)
        #pragma unroll
        for (int j = 0; j < 4; ++j) acc[i][j] = zero4;

    const unsigned short* Pb = P  + (size_t)b * N_ * N_;
    const unsigned short* Vb = vT + (size_t)b * C_ * N_;

    auto stage = [&](int buf, int kk) {
        #pragma unroll
        for (int i = 0; i < 4; ++i) {
            int f = wave * 4 + i;
            int t = f >> 1, kq = f & 1;
            g2l16(Pb + (size_t)(m0 + t * 16 + lr) * N_ + kk + kq * 32 + lk * 8,
                  &As[buf][f * 512]);
            g2l16(Vb + (size_t)(c0 + t * 16 + lr) * N_ + kk + kq * 32 + lk * 8,
                  &Bs[buf][f * 512]);
        }
    };

    stage(0, 0);
    __syncthreads();                           // vmcnt(0) drain at barrier
    int cur = 0;
    for (int kk = 64; kk < N_; kk += 64) {
        bf8 a[2][4], bb[2][4];
        #pragma unroll
        for (int kq = 0; kq < 2; ++kq) {
            #pragma unroll
            for (int ti = 0; ti < 4; ++ti)
                a[kq][ti] = *(const bf8*)&As[cur][((wm * 4 + ti) * 2 + kq) * 512 + lane * 8];
            #pragma unroll
            for (int tj = 0; tj < 4; ++tj)
                bb[kq][tj] = *(const bf8*)&Bs[cur][((wn * 4 + tj) * 2 + kq) * 512 + lane * 8];
        }
        // pin: ds_reads stay above the LDS-writing prefetch (no vmcnt before them)
        __builtin_amdgcn_sched_barrier(0);
        stage(cur ^ 1, kk);                    // prefetch next tile; drains at barrier
        #pragma unroll
        for (int kq = 0; kq < 2; ++kq)
            #pragma unroll
            for (int ti = 0; ti < 4; ++ti)
                #pragma unroll
                for (int tj = 0; tj < 4; ++tj)
                    acc[ti][tj] = MFMA16(a[kq][ti], bb[kq][tj], acc[ti][tj]);
        __syncthreads();
        cur ^= 1;
    }
    {   // tail: compute last staged tile (no prefetch)
        #pragma unroll
        for (int kq = 0; kq < 2; ++kq) {
            bf8 a[4], bb[4];
            #pragma unroll
            for (int ti = 0; ti < 4; ++ti)
                a[ti] = *(const bf8*)&As[cur][((wm * 4 + ti) * 2 + kq) * 512 + lane * 8];
            #pragma unroll
            for (int tj = 0; tj < 4; ++tj)
                bb[tj] = *(const bf8*)&Bs[cur][((wn * 4 + tj) * 2 + kq) * 512 + lane * 8];
            #pragma unroll
            for (int ti = 0; ti < 4; ++ti)
                #pragma unroll
                for (int tj = 0; tj < 4; ++tj)
                    acc[ti][tj] = MFMA16(a[ti], bb[tj], acc[ti][tj]);
        }
    }

    #pragma unroll
    for (int ti = 0; ti < 4; ++ti)
        #pragma unroll
        for (int tj = 0; tj < 4; ++tj) {
            int col = c0 + wn * 64 + tj * 16 + lr;
            #pragma unroll
            for (int r = 0; r < 4; ++r) {
                int row = m0 + wm * 64 + ti * 16 + lk * 4 + r;
                size_t idx = (size_t)(b * N_ + row) * C_ + col;
                out[idx] = acc[ti][tj][r] + x[idx];
            }
        }
}

// ---------------------------------------------------------------------------
extern "C" void kernel_launch(void* const* d_in, const int* in_sizes, int n_in,
                              void* d_out, int out_size, void* d_ws, size_t ws_size,
                              hipStream_t stream) {
    (void)in_sizes; (void)n_in; (void)out_size; (void)ws_size;
    const float* xf = (const float*)d_in[0];
    const float* wq = (const float*)d_in[1];
    const float* bq = (const float*)d_in[2];
    const float* wk = (const float*)d_in[3];
    const float* bk = (const float*)d_in[4];
    const float* wv = (const float*)d_in[5];
    const float* bv = (const float*)d_in[6];
    float* out = (float*)d_out;

    // workspace layout (bytes), total needed ~109 MB:
    //   q [0,4MB) | k [4MB,8MB) | vT [8MB,40MB)
    //   WT (655KB) + xb (32MB) in [40MB, 76MB)  -- dead after qkv
    //   P (64MB) aliased over WT+xb region starting 41,943,040
    char* ws = (char*)d_ws;
    unsigned short* qb  = (unsigned short*)(ws);
    unsigned short* kb  = (unsigned short*)(ws + 4194304);
    unsigned short* vTb = (unsigned short*)(ws + 8388608);
    unsigned short* WT  = (unsigned short*)(ws + 41943040);  // [640][512]
    unsigned short* xb  = (unsigned short*)(ws + 42598400);
    unsigned short* Pb  = (unsigned short*)(ws + 41943040);  // overlaps WT+xb

    xcvt<<<16384, 256, 0, stream>>>(xf, xb);                 // 16.7M elems
    wtrans_all<<<1280, 256, 0, stream>>>(wq, wk, wv, WT);    // all 640 rows
    qkv<<<dim3(256, 5), 256, 0, stream>>>(xb, WT, bq, bk, bv, qb, kb, vTb);
    scores<<<dim3(64, 32), 256, 0, stream>>>(qb, kb, Pb);
    pv<<<dim3(8, 4, 32), 256, 0, stream>>>(Pb, vTb, xf, out);
}

// Round 2
// 284.439 us; speedup vs baseline: 1.0354x; 1.0124x over previous
//
#include <hip/hip_runtime.h>
#include <stdint.h>

// SelfAttentionLayer: x [32,32,32,512] fp32 -> out fp32 same shape
#define B_ 32
#define N_ 1024   // tokens per batch (H*W)
#define C_ 512
#define D_ 64     // DQK

typedef __attribute__((ext_vector_type(8))) __bf16 bf8;   // MFMA A/B frag (4 VGPRs)
typedef __attribute__((ext_vector_type(4))) float f32x4;  // MFMA C/D frag

typedef const __attribute__((address_space(1))) void* gp_t;
typedef __attribute__((address_space(3))) void* lp_t;

__device__ inline void g2l16(const void* g, void* l) {
    // async global->LDS, 16B/lane; LDS dest = uniform base + lane*16
    __builtin_amdgcn_global_load_lds((gp_t)g, (lp_t)l, 16, 0, 0);
}

__device__ inline float b2f(unsigned short u) {
    return __uint_as_float(((unsigned)u) << 16);
}
__device__ inline unsigned short f2b(float f) {   // f32 -> bf16 bits, RNE
    unsigned u = __float_as_uint(f);
    u += 0x7FFF + ((u >> 16) & 1);
    return (unsigned short)(u >> 16);
}

#define MFMA16(a, b, c) __builtin_amdgcn_mfma_f32_16x16x32_bf16((a), (b), (c), 0, 0, 0)

// fragment loads from a staged (frag-order) 128x64 tile pair
__device__ __forceinline__ void ld_frags(const unsigned short* As, const unsigned short* Bs,
                                         int wm, int wn, int lane,
                                         bf8 (&a)[2][4], bf8 (&bb)[2][4]) {
    #pragma unroll
    for (int kq = 0; kq < 2; ++kq) {
        #pragma unroll
        for (int ti = 0; ti < 4; ++ti)
            a[kq][ti] = *(const bf8*)&As[((wm * 4 + ti) * 2 + kq) * 512 + lane * 8];
        #pragma unroll
        for (int tj = 0; tj < 4; ++tj)
            bb[kq][tj] = *(const bf8*)&Bs[((wn * 4 + tj) * 2 + kq) * 512 + lane * 8];
    }
}

__device__ __forceinline__ void do_mfma(const bf8 (&a)[2][4], const bf8 (&bb)[2][4],
                                        f32x4 (&acc)[4][4]) {
    #pragma unroll
    for (int kq = 0; kq < 2; ++kq)
        #pragma unroll
        for (int ti = 0; ti < 4; ++ti)
            #pragma unroll
            for (int tj = 0; tj < 4; ++tj)
                acc[ti][tj] = MFMA16(a[kq][ti], bb[kq][tj], acc[ti][tj]);
}

// ---------------------------------------------------------------------------
// Kernel 0: x fp32 -> bf16 (so qkv can stage via global_load_lds)
// ---------------------------------------------------------------------------
__global__ __launch_bounds__(256) void xcvt(const float* __restrict__ x,
                                            unsigned short* __restrict__ xb) {
    int i = blockIdx.x * 256 + threadIdx.x;      // quad index, exact grid
    float4 f = ((const float4*)x)[i];
    ushort4 o;
    o.x = f2b(f.x); o.y = f2b(f.y); o.z = f2b(f.z); o.w = f2b(f.w);
    ((ushort4*)xb)[i] = o;
}

// ---------------------------------------------------------------------------
// Kernel 0b: weight transpose + cvt into concatenated WT[640][512] bf16.
// ---------------------------------------------------------------------------
__global__ __launch_bounds__(256) void wtrans_all(
    const float* __restrict__ wq, const float* __restrict__ wk,
    const float* __restrict__ wv, unsigned short* __restrict__ wt)
{
    int t = blockIdx.x * 256 + threadIdx.x;      // output-linear, exact grid (640*512)
    int co = t >> 9;          // /512
    int ci = t & 511;
    const float* src;
    int col, cout;
    if (co < 64)       { src = wq; col = co;       cout = 64;  }
    else if (co < 128) { src = wk; col = co - 64;  cout = 64;  }
    else               { src = wv; col = co - 128; cout = 512; }
    wt[t] = f2b(src[(size_t)ci * cout + col]);
}

// ---------------------------------------------------------------------------
// Kernel 1: QKV projection GEMM. [32768,512]bf16 @ WT[640,512]^T.
// Block tile 128x128, waves 2x2 (64x64 each), BK=64, both operands staged
// fragment-order via global_load_lds.  2-deep counted-vmcnt pipeline:
// 16 loads/wave in flight; per iter {vmcnt(8); bar; ds_read; lgkmcnt(0);
// bar; restage(t+2); MFMA}.  vmcnt never drains to 0 in the main loop.
// grid = (256 rowblocks, 5 colblocks): cb 0 -> q|k cols, cb 1..4 -> v cols.
// v written transposed vT[b][c][n] via LDS transpose buffer (aliased).
// ---------------------------------------------------------------------------
__global__ __launch_bounds__(256) void qkv(
    const unsigned short* __restrict__ xb,
    const unsigned short* __restrict__ WT,
    const float* __restrict__ bq, const float* __restrict__ bk,
    const float* __restrict__ bv,
    unsigned short* __restrict__ q, unsigned short* __restrict__ k,
    unsigned short* __restrict__ vT)
{
    const int rb = blockIdx.x;
    const int cb = blockIdx.y;
    const int tid = threadIdx.x;
    const int lane = tid & 63;
    const int wave = tid >> 6;
    const int wm = wave >> 1, wn = wave & 1;
    const int lr = lane & 15;     // frag row/col within 16
    const int lk = lane >> 4;     // k-octet 0..3

    __shared__ unsigned short SM[32768];      // 64 KB: As[2][8192] | Bs[2][8192]
    unsigned short* TB = SM;                  // aliased transpose buf 128x132 (16896)

    const int row0 = rb * 128;
    const int col0 = cb * 128;                // within [640]

    f32x4 zero4 = {0.f, 0.f, 0.f, 0.f};
    f32x4 acc[4][4];
    #pragma unroll
    for (int i = 0; i < 4; ++i)
        #pragma unroll
        for (int j = 0; j < 4; ++j) acc[i][j] = zero4;

    auto stage = [&](int buf, int kk) {       // 8 loads/wave
        unsigned short* As = SM + buf * 8192;
        unsigned short* Bs = SM + 16384 + buf * 8192;
        #pragma unroll
        for (int i = 0; i < 4; ++i) {          // 16 frags each for A and B
            int f = wave * 4 + i;
            int t = f >> 1, kq = f & 1;
            g2l16(xb + (size_t)(row0 + t * 16 + lr) * C_ + kk + kq * 32 + lk * 8,
                  &As[f * 512]);
            g2l16(WT + (size_t)(col0 + t * 16 + lr) * C_ + kk + kq * 32 + lk * 8,
                  &Bs[f * 512]);
        }
    };

    stage(0, 0);
    stage(1, 64);
    int cur = 0;
    for (int t = 0; t < 6; ++t) {             // steady state: tiles 0..5
        asm volatile("s_waitcnt vmcnt(8)" ::: "memory");   // tile t landed
        __builtin_amdgcn_s_barrier();
        bf8 a[2][4], bb[2][4];
        ld_frags(SM + cur * 8192, SM + 16384 + cur * 8192, wm, wn, lane, a, bb);
        asm volatile("s_waitcnt lgkmcnt(0)" ::: "memory"); // my reads done
        __builtin_amdgcn_s_barrier();                       // everyone's reads done
        stage(cur, (t + 2) * 64);             // reuse buffer for tile t+2
        do_mfma(a, bb, acc);
        cur ^= 1;
    }
    {   // tile 6: wait oldest 8, tile 7 still in flight
        asm volatile("s_waitcnt vmcnt(8)" ::: "memory");
        __builtin_amdgcn_s_barrier();
        bf8 a[2][4], bb[2][4];
        ld_frags(SM + cur * 8192, SM + 16384 + cur * 8192, wm, wn, lane, a, bb);
        do_mfma(a, bb, acc);
        cur ^= 1;
    }
    {   // tile 7: final drain
        asm volatile("s_waitcnt vmcnt(0)" ::: "memory");
        __builtin_amdgcn_s_barrier();
        bf8 a[2][4], bb[2][4];
        ld_frags(SM + cur * 8192, SM + 16384 + cur * 8192, wm, wn, lane, a, bb);
        do_mfma(a, bb, acc);
    }

    if (cb == 0) {
        // wn==0 waves own cols 0..63 (-> q), wn==1 own cols 64..127 (-> k)
        unsigned short* outp = (wn == 0) ? q : k;
        const float* bias = (wn == 0) ? bq : bk;
        #pragma unroll
        for (int ti = 0; ti < 4; ++ti)
            #pragma unroll
            for (int tj = 0; tj < 4; ++tj) {
                int col = tj * 16 + lr;           // 0..63 within q or k
                float bi = bias[col];
                #pragma unroll
                for (int r = 0; r < 4; ++r) {
                    int row = row0 + wm * 64 + ti * 16 + lk * 4 + r;
                    outp[(size_t)row * D_ + col] = f2b(acc[ti][tj][r] + bi);
                }
            }
    } else {
        const int colv = (cb - 1) * 128;          // v col base (0..511)
        __syncthreads();                          // all frag reads done; TB aliases SM
        #pragma unroll
        for (int ti = 0; ti < 4; ++ti)
            #pragma unroll
            for (int tj = 0; tj < 4; ++tj) {
                int c = wn * 64 + tj * 16 + lr;   // 0..127 within block
                float bi = bv[colv + c];
                int tok = wm * 64 + ti * 16 + lk * 4;
                ushort4 o;
                o.x = f2b(acc[ti][tj][0] + bi);
                o.y = f2b(acc[ti][tj][1] + bi);
                o.z = f2b(acc[ti][tj][2] + bi);
                o.w = f2b(acc[ti][tj][3] + bi);
                *(ushort4*)&TB[c * 132 + tok] = o;
            }
        __syncthreads();
        const int b  = row0 >> 10;
        const int n0 = row0 & 1023;
        #pragma unroll
        for (int i = 0; i < 16; ++i) {
            int idx = tid + 256 * i;              // 0..4095
            int c = idx >> 5, ch = idx & 31;
            ushort4 t4 = *(const ushort4*)&TB[c * 132 + ch * 4];
            *(ushort4*)&vT[((size_t)(b * C_ + colv + c)) * N_ + n0 + ch * 4] = t4;
        }
    }
}

// ---------------------------------------------------------------------------
// Kernel 2: scores + softmax -> P bf16 [b][n][m].
// ---------------------------------------------------------------------------
#define SLD 1032   // S leading dim (shorts), pad 8 to break 2048B bank period
__global__ __launch_bounds__(256) void scores(
    const unsigned short* __restrict__ q,
    const unsigned short* __restrict__ k,
    unsigned short* __restrict__ P)
{
    const int qt = blockIdx.x, b = blockIdx.y;
    const int tid = threadIdx.x, lane = tid & 63, wave = tid >> 6;
    const int lr = lane & 15, lk = lane >> 4;
    __shared__ unsigned short S[16 * SLD];      // bf16 scores, 33 KB

    const int n0 = qt * 16;
    const unsigned short* qrow = q + (size_t)(b * N_ + n0 + lr) * D_ + lk * 8;
    bf8 qa0 = *(const bf8*)(qrow);
    bf8 qa1 = *(const bf8*)(qrow + 32);

    const int m0w = wave * 256;
    #pragma unroll 4
    for (int mt = 0; mt < 16; ++mt) {
        int m = m0w + mt * 16;
        const unsigned short* krow = k + (size_t)(b * N_ + m + lr) * D_ + lk * 8;
        bf8 kb0 = *(const bf8*)(krow);
        bf8 kb1 = *(const bf8*)(krow + 32);
        f32x4 s = {0.f, 0.f, 0.f, 0.f};
        s = MFMA16(qa0, kb0, s);
        s = MFMA16(qa1, kb1, s);
        #pragma unroll
        for (int r = 0; r < 4; ++r)
            S[(lk * 4 + r) * SLD + m + lr] = f2b(s[r] * 0.125f);  // 1/sqrt(64)
    }
    __syncthreads();

    #pragma unroll
    for (int rr4 = 0; rr4 < 4; ++rr4) {
        int rr = wave * 4 + rr4;
        float vals[16];
        float mx = -1e30f;
        #pragma unroll
        for (int j = 0; j < 16; ++j) {
            vals[j] = b2f(S[rr * SLD + j * 64 + lane]);
            mx = fmaxf(mx, vals[j]);
        }
        #pragma unroll
        for (int off = 32; off; off >>= 1) mx = fmaxf(mx, __shfl_xor(mx, off));
        float sum = 0.f;
        #pragma unroll
        for (int j = 0; j < 16; ++j) { vals[j] = __expf(vals[j] - mx); sum += vals[j]; }
        #pragma unroll
        for (int off = 32; off; off >>= 1) sum += __shfl_xor(sum, off);
        float inv = 1.f / sum;
        unsigned short* pp = P + (size_t)(b * N_ + n0 + rr) * N_;
        #pragma unroll
        for (int j = 0; j < 16; ++j) pp[j * 64 + lane] = f2b(vals[j] * inv);
    }
}

// ---------------------------------------------------------------------------
// Kernel 3: O = P @ V + x (residual), fp32 out. Per-batch GEMM M=1024 N=512
// K=1024. Block tile 128x128, waves 2x2, BK=64.  2-deep counted-vmcnt
// pipeline (same schedule as qkv).  grid = (8, 4, 32)
// ---------------------------------------------------------------------------
__global__ __launch_bounds__(256) void pv(
    const unsigned short* __restrict__ P,
    const unsigned short* __restrict__ vT,
    const float* __restrict__ x,
    float* __restrict__ out)
{
    const int m0 = blockIdx.x * 128, c0 = blockIdx.y * 128, b = blockIdx.z;
    const int tid = threadIdx.x, lane = tid & 63, wave = tid >> 6;
    const int wm = wave >> 1, wn = wave & 1;
    const int lr = lane & 15, lk = lane >> 4;

    __shared__ unsigned short As[2][8192];   // P frags, double-buffered
    __shared__ unsigned short Bs[2][8192];   // V frags, double-buffered

    f32x4 zero4 = {0.f, 0.f, 0.f, 0.f};
    f32x4 acc[4][4];
    #pragma unroll
    for (int i = 0; i < 4; ++i)
        #pragma unroll
        for (int j = 0; j < 4; ++j) acc[i][j] = zero4;

    const unsigned short* Pb = P  + (size_t)b * N_ * N_;
    const unsigned short* Vb = vT + (size_t)b * C_ * N_;

    auto stage = [&](int buf, int kk) {       // 8 loads/wave
        #pragma unroll
        for (int i = 0; i < 4; ++i) {
            int f = wave * 4 + i;
            int t = f >> 1, kq = f & 1;
            g2l16(Pb + (size_t)(m0 + t * 16 + lr) * N_ + kk + kq * 32 + lk * 8,
                  &As[buf][f * 512]);
            g2l16(Vb + (size_t)(c0 + t * 16 + lr) * N_ + kk + kq * 32 + lk * 8,
                  &Bs[buf][f * 512]);
        }
    };

    stage(0, 0);
    stage(1, 64);
    int cur = 0;
    for (int t = 0; t < 14; ++t) {            // steady state: tiles 0..13
        asm volatile("s_waitcnt vmcnt(8)" ::: "memory");   // tile t landed
        __builtin_amdgcn_s_barrier();
        bf8 a[2][4], bb[2][4];
        ld_frags(&As[cur][0], &Bs[cur][0], wm, wn, lane, a, bb);
        asm volatile("s_waitcnt lgkmcnt(0)" ::: "memory"); // my reads done
        __builtin_amdgcn_s_barrier();                       // everyone's reads done
        stage(cur, (t + 2) * 64);             // reuse buffer for tile t+2
        do_mfma(a, bb, acc);
        cur ^= 1;
    }
    {   // tile 14: wait oldest 8, tile 15 still in flight
        asm volatile("s_waitcnt vmcnt(8)" ::: "memory");
        __builtin_amdgcn_s_barrier();
        bf8 a[2][4], bb[2][4];
        ld_frags(&As[cur][0], &Bs[cur][0], wm, wn, lane, a, bb);
        do_mfma(a, bb, acc);
        cur ^= 1;
    }
    {   // tile 15: final drain
        asm volatile("s_waitcnt vmcnt(0)" ::: "memory");
        __builtin_amdgcn_s_barrier();
        bf8 a[2][4], bb[2][4];
        ld_frags(&As[cur][0], &Bs[cur][0], wm, wn, lane, a, bb);
        do_mfma(a, bb, acc);
    }

    #pragma unroll
    for (int ti = 0; ti < 4; ++ti)
        #pragma unroll
        for (int tj = 0; tj < 4; ++tj) {
            int col = c0 + wn * 64 + tj * 16 + lr;
            #pragma unroll
            for (int r = 0; r < 4; ++r) {
                int row = m0 + wm * 64 + ti * 16 + lk * 4 + r;
                size_t idx = (size_t)(b * N_ + row) * C_ + col;
                out[idx] = acc[ti][tj][r] + x[idx];
            }
        }
}

// ---------------------------------------------------------------------------
extern "C" void kernel_launch(void* const* d_in, const int* in_sizes, int n_in,
                              void* d_out, int out_size, void* d_ws, size_t ws_size,
                              hipStream_t stream) {
    (void)in_sizes; (void)n_in; (void)out_size; (void)ws_size;
    const float* xf = (const float*)d_in[0];
    const float* wq = (const float*)d_in[1];
    const float* bq = (const float*)d_in[2];
    const float* wk = (const float*)d_in[3];
    const float* bk = (const float*)d_in[4];
    const float* wv = (const float*)d_in[5];
    const float* bv = (const float*)d_in[6];
    float* out = (float*)d_out;

    // workspace layout (bytes), total needed ~109 MB:
    //   q [0,4MB) | k [4MB,8MB) | vT [8MB,40MB)
    //   WT (655KB) + xb (32MB) in [40MB, 76MB)  -- dead after qkv
    //   P (64MB) aliased over WT+xb region starting 41,943,040
    char* ws = (char*)d_ws;
    unsigned short* qb  = (unsigned short*)(ws);
    unsigned short* kb  = (unsigned short*)(ws + 4194304);
    unsigned short* vTb = (unsigned short*)(ws + 8388608);
    unsigned short* WT  = (unsigned short*)(ws + 41943040);  // [640][512]
    unsigned short* xb  = (unsigned short*)(ws + 42598400);
    unsigned short* Pb  = (unsigned short*)(ws + 41943040);  // overlaps WT+xb

    xcvt<<<16384, 256, 0, stream>>>(xf, xb);                 // 16.7M elems
    wtrans_all<<<1280, 256, 0, stream>>>(wq, wk, wv, WT);    // all 640 rows
    qkv<<<dim3(256, 5), 256, 0, stream>>>(xb, WT, bq, bk, bv, qb, kb, vTb);
    scores<<<dim3(64, 32), 256, 0, stream>>>(qb, kb, Pb);
    pv<<<dim3(8, 4, 32), 256, 0, stream>>>(Pb, vTb, xf, out);
}